// Round 1
// baseline (464.006 us; speedup 1.0000x reference)
//
#include <hip/hip_runtime.h>

// Deformable conv v1 fwd: B=4, C=64, H=W=128, K=3, O=64, fp32.
// ws layout (floats):
//   [0)        wT      576*64   = 36864   (w transposed: wT[ck*64+o])
//   [36864)    w_offT  576*18   = 10368   (w_off transposed: [ck*18+ch])
//   [65536)    xt      B*H*W*C  = 4194304 (x in NHWC)
//   [4259840)  off_pix B*H*W*18 = 1179648 (offset conv out, pixel-major)
// total ~21.8 MB

#define HH 128
#define WW 128
#define CC 64
#define NB 4

__global__ __launch_bounds__(256) void prep_weights(
    const float* __restrict__ w, const float* __restrict__ w_off,
    float* __restrict__ wT, float* __restrict__ w_offT) {
  int t = blockIdx.x * 256 + threadIdx.x;
  int stride = gridDim.x * 256;
  for (int i = t; i < 64 * 576; i += stride) {
    int o = i / 576, ck = i - o * 576;
    wT[ck * 64 + o] = w[i];
  }
  for (int i = t; i < 18 * 576; i += stride) {
    int ch = i / 576, ck = i - ch * 576;
    w_offT[ck * 18 + ch] = w_off[i];
  }
}

// NCHW -> NHWC, LDS tile transpose. blk = b*256 + h*2 + wchunk
__global__ __launch_bounds__(256) void transpose_x(
    const float* __restrict__ x, float* __restrict__ xt) {
  __shared__ float tile[64][65];
  int blk = blockIdx.x;
  int wchunk = blk & 1;
  int h = (blk >> 1) & 127;
  int b = blk >> 8;
  int w0 = wchunk * 64;
  int r = threadIdx.x >> 6;      // 0..3
  int lane = threadIdx.x & 63;
#pragma unroll
  for (int i = 0; i < 16; i++) {
    int c = r + i * 4;
    tile[c][lane] = x[(((size_t)(b * 64 + c) * 128) + h) * 128 + w0 + lane];
  }
  __syncthreads();
#pragma unroll
  for (int i = 0; i < 16; i++) {
    int wi = r + i * 4;
    xt[(((size_t)(b * 128 + h) * 128) + w0 + wi) * 64 + lane] = tile[lane][wi];
  }
}

// Offset conv: one thread per pixel, all 18 output channels.
// Weights read wave-uniform (scalar loads), x as float4 from NHWC.
__global__ __launch_bounds__(256) void offset_conv(
    const float* __restrict__ xt, const float* __restrict__ w_offT,
    const float* __restrict__ b_off, float* __restrict__ off_pix) {
  int g = blockIdx.x * 256 + threadIdx.x;   // b*16384 + h*128 + w
  int b = g >> 14;
  int hw = g & 16383;
  int h = hw >> 7;
  int w = hw & 127;
  float acc[18];
#pragma unroll
  for (int ch = 0; ch < 18; ch++) acc[ch] = b_off[ch];

  for (int ky = 0; ky < 3; ky++) {
    int y = h + ky - 1;
    if ((unsigned)y >= 128u) continue;
    for (int kx = 0; kx < 3; kx++) {
      int xx = w + kx - 1;
      if ((unsigned)xx >= 128u) continue;
      int tap = ky * 3 + kx;
      const float* xp = xt + ((size_t)(b * 128 + y) * 128 + xx) * 64;
      for (int c = 0; c < 64; c += 4) {
        float4 xv = *reinterpret_cast<const float4*>(xp + c);
        const float* xs = reinterpret_cast<const float*>(&xv);
#pragma unroll
        for (int j = 0; j < 4; j++) {
          const float* wrow = w_offT + ((c + j) * 9 + tap) * 18;
          float xv1 = xs[j];
#pragma unroll
          for (int ch = 0; ch < 18; ch++) acc[ch] += xv1 * wrow[ch];
        }
      }
    }
  }
  float* op = off_pix + (size_t)g * 18;
#pragma unroll
  for (int ch = 0; ch < 18; ch++) op[ch] = acc[ch];
}

// Fused bilinear sample + GEMM.
// Block: 16 pixels of one row. blk = b*1024 + h*8 + wchunk.
// Phase 1: 4 waves x 36 (pixel,tap) pairs, lanes = channels -> LDS.
// Phase 2: thread = (pixel p = t&15, og = t>>4 -> o = og*4..+3).
#define SROW 580   // LDS row stride (floats): 580%32=4 (2-way, free), rows 16B aligned
__global__ __launch_bounds__(256) void dcn_main(
    const float* __restrict__ xt, const float* __restrict__ off_pix,
    const float* __restrict__ wT, const float* __restrict__ bias,
    float* __restrict__ out) {
  __shared__ __align__(16) float s[16 * SROW];
  int blk = blockIdx.x;
  int wchunk = blk & 7;
  int h = (blk >> 3) & 127;
  int b = blk >> 10;
  int w0 = wchunk * 16;
  int lane = threadIdx.x & 63;
  int wave = threadIdx.x >> 6;

  const float* xbase = xt + (size_t)b * 128 * 128 * 64;

  // ---- Phase 1: bilinear sampling into LDS ----
#pragma unroll 2
  for (int i = 0; i < 36; i++) {
    int pr = wave * 36 + i;
    int p = pr / 9;
    int k = pr - p * 9;
    int ky = k / 3, kx = k - ky * 3;
    const float* offp = off_pix + ((size_t)((b * 128 + h) * 128 + w0 + p)) * 18;
    float oy = offp[2 * k];
    float ox = offp[2 * k + 1];
    float yf = (float)(h + ky - 1) + oy;
    float xf = (float)(w0 + p + kx - 1) + ox;
    float y0f = floorf(yf), x0f = floorf(xf);
    float wy = yf - y0f, wx = xf - x0f;
    int y0 = (int)y0f, x0 = (int)x0f;
    int y1 = y0 + 1, x1 = x0 + 1;
    float w00 = (1.f - wy) * (1.f - wx);
    float w01 = (1.f - wy) * wx;
    float w10 = wy * (1.f - wx);
    float w11 = wy * wx;
    bool vy0 = (unsigned)y0 < 128u, vy1 = (unsigned)y1 < 128u;
    bool vx0 = (unsigned)x0 < 128u, vx1 = (unsigned)x1 < 128u;
    if (!(vy0 && vx0)) w00 = 0.f;
    if (!(vy0 && vx1)) w01 = 0.f;
    if (!(vy1 && vx0)) w10 = 0.f;
    if (!(vy1 && vx1)) w11 = 0.f;
    int y0c = min(max(y0, 0), 127), y1c = min(max(y1, 0), 127);
    int x0c = min(max(x0, 0), 127), x1c = min(max(x1, 0), 127);
    float v00 = xbase[((size_t)(y0c * 128 + x0c)) * 64 + lane];
    float v01 = xbase[((size_t)(y0c * 128 + x1c)) * 64 + lane];
    float v10 = xbase[((size_t)(y1c * 128 + x0c)) * 64 + lane];
    float v11 = xbase[((size_t)(y1c * 128 + x1c)) * 64 + lane];
    float accv = w00 * v00 + w01 * v01 + w10 * v10 + w11 * v11;
    s[p * SROW + lane * 9 + k] = accv;
  }
  __syncthreads();

  // ---- Phase 2: GEMM out[o][p] = sum_ck s[p][ck] * wT[ck][o] ----
  int p = threadIdx.x & 15;
  int og = threadIdx.x >> 4;   // 0..15
  const float* sp = s + p * SROW;
  const float* wp = wT + og * 4;
  float ax = 0.f, ay = 0.f, az = 0.f, aw = 0.f;
#pragma unroll 2
  for (int ck4 = 0; ck4 < 144; ck4++) {
    float4 sv = *reinterpret_cast<const float4*>(sp + ck4 * 4);
    const float* svf = reinterpret_cast<const float*>(&sv);
#pragma unroll
    for (int u = 0; u < 4; u++) {
      int ck = ck4 * 4 + u;
      float4 wv = *reinterpret_cast<const float4*>(wp + (size_t)ck * 64);
      float s1 = svf[u];
      ax += s1 * wv.x;
      ay += s1 * wv.y;
      az += s1 * wv.z;
      aw += s1 * wv.w;
    }
  }
  int o0 = og * 4;
  float4 bv = *reinterpret_cast<const float4*>(bias + o0);
  size_t obase = ((size_t)(b * 64 + o0)) * 16384 + h * 128 + w0 + p;
  out[obase]           = ax + bv.x;
  out[obase + 16384]   = ay + bv.y;
  out[obase + 32768]   = az + bv.z;
  out[obase + 49152]   = aw + bv.w;
}

extern "C" void kernel_launch(void* const* d_in, const int* in_sizes, int n_in,
                              void* d_out, int out_size, void* d_ws, size_t ws_size,
                              hipStream_t stream) {
  const float* x     = (const float*)d_in[0];
  const float* w_off = (const float*)d_in[1];
  const float* b_off = (const float*)d_in[2];
  const float* w     = (const float*)d_in[3];
  const float* b     = (const float*)d_in[4];
  float* out = (float*)d_out;
  float* ws = (float*)d_ws;

  float* wT      = ws;
  float* w_offT  = ws + 36864;
  float* xt      = ws + 65536;
  float* off_pix = ws + 4259840;

  prep_weights<<<64, 256, 0, stream>>>(w, w_off, wT, w_offT);
  transpose_x<<<1024, 256, 0, stream>>>(x, xt);
  offset_conv<<<256, 256, 0, stream>>>(xt, w_offT, b_off, off_pix);
  dcn_main<<<4096, 256, 0, stream>>>(xt, off_pix, wT, b, out);
}

// Round 2
// 239.166 us; speedup vs baseline: 1.9401x; 1.9401x over previous
//
#include <hip/hip_runtime.h>

// Deformable conv v1 fwd: B=4, C=64, H=W=128, K=3, O=64, fp32.
// ws layout (floats):
//   [0)        wT      9*64*64 = 36864   (wT[k][c][o])
//   [36864)    w_offT  576*18  = 10368   ([ck][18], ck=c*9+tap)
//   [65536)    xt      4*128*128*64 = 4194304 (x in NHWC)
//   [4259840)  off_pix 4*128*128*18 = 1179648 (offset conv out, pixel-major)

__global__ __launch_bounds__(256) void prep_weights(
    const float* __restrict__ w, const float* __restrict__ w_off,
    float* __restrict__ wT, float* __restrict__ w_offT) {
  int t = blockIdx.x * 256 + threadIdx.x;
  int stride = gridDim.x * 256;
  // wT[k*4096 + c*64 + o] = w[o*576 + c*9 + k]
  for (int i = t; i < 9 * 64 * 64; i += stride) {
    int k = i >> 12, c = (i >> 6) & 63, o = i & 63;
    wT[i] = w[o * 576 + c * 9 + k];
  }
  for (int i = t; i < 18 * 576; i += stride) {
    int ch = i / 576, ck = i - ch * 576;
    w_offT[ck * 18 + ch] = w_off[i];
  }
}

// NCHW -> NHWC, LDS tile transpose. blk = b*256 + h*2 + wchunk
__global__ __launch_bounds__(256) void transpose_x(
    const float* __restrict__ x, float* __restrict__ xt) {
  __shared__ float tile[64][65];
  int blk = blockIdx.x;
  int wchunk = blk & 1;
  int h = (blk >> 1) & 127;
  int b = blk >> 8;
  int w0 = wchunk * 64;
  int r = threadIdx.x >> 6;
  int lane = threadIdx.x & 63;
#pragma unroll
  for (int i = 0; i < 16; i++) {
    int c = r + i * 4;
    tile[c][lane] = x[(((size_t)(b * 64 + c) * 128) + h) * 128 + w0 + lane];
  }
  __syncthreads();
#pragma unroll
  for (int i = 0; i < 16; i++) {
    int wi = r + i * 4;
    xt[(((size_t)(b * 128 + h) * 128) + w0 + wi) * 64 + lane] = tile[lane][wi];
  }
}

// Offset conv: one thread per pixel, all 18 output channels.
// Weights staged once per block in LDS; broadcast vector reads.
__global__ __launch_bounds__(256) void offset_conv(
    const float* __restrict__ xt, const float* __restrict__ w_offT,
    const float* __restrict__ b_off, float* __restrict__ off_pix) {
  __shared__ __align__(16) float wl[576 * 20];  // [ck][20], 18 used
  int tid = threadIdx.x;
  for (int i = tid; i < 10368; i += 256) {
    int ck = i / 18;
    int ch = i - ck * 18;
    wl[ck * 20 + ch] = w_offT[i];
  }
  __syncthreads();

  int g = blockIdx.x * 256 + tid;   // b*16384 + h*128 + w
  int b = g >> 14;
  int hw = g & 16383;
  int h = hw >> 7;
  int w = hw & 127;
  float acc[18];
#pragma unroll
  for (int ch = 0; ch < 18; ch++) acc[ch] = b_off[ch];

  for (int ky = 0; ky < 3; ky++) {
    int y = h + ky - 1;
    if ((unsigned)y >= 128u) continue;
    for (int kx = 0; kx < 3; kx++) {
      int xx = w + kx - 1;
      if ((unsigned)xx >= 128u) continue;
      int tap = ky * 3 + kx;
      const float* xp = xt + ((size_t)(b * 128 + y) * 128 + xx) * 64;
      for (int c4 = 0; c4 < 16; c4++) {
        float4 xv = *reinterpret_cast<const float4*>(xp + c4 * 4);
        const float* xs = reinterpret_cast<const float*>(&xv);
#pragma unroll
        for (int j = 0; j < 4; j++) {
          const float* wr = &wl[((c4 * 4 + j) * 9 + tap) * 20];
          float xj = xs[j];
          float4 w0v = *reinterpret_cast<const float4*>(wr);
          float4 w1v = *reinterpret_cast<const float4*>(wr + 4);
          float4 w2v = *reinterpret_cast<const float4*>(wr + 8);
          float4 w3v = *reinterpret_cast<const float4*>(wr + 12);
          float2 w4v = *reinterpret_cast<const float2*>(wr + 16);
          acc[0]  += xj * w0v.x; acc[1]  += xj * w0v.y; acc[2]  += xj * w0v.z; acc[3]  += xj * w0v.w;
          acc[4]  += xj * w1v.x; acc[5]  += xj * w1v.y; acc[6]  += xj * w1v.z; acc[7]  += xj * w1v.w;
          acc[8]  += xj * w2v.x; acc[9]  += xj * w2v.y; acc[10] += xj * w2v.z; acc[11] += xj * w2v.w;
          acc[12] += xj * w3v.x; acc[13] += xj * w3v.y; acc[14] += xj * w3v.z; acc[15] += xj * w3v.w;
          acc[16] += xj * w4v.x; acc[17] += xj * w4v.y;
        }
      }
    }
  }
  float* op = off_pix + (size_t)g * 18;
#pragma unroll
  for (int ch = 0; ch < 18; ch++) op[ch] = acc[ch];
}

// Fused bilinear sample + register-tiled GEMM.
// Block: 64 pixels of one row (blk = b*256 + h*2 + wchunk), 256 threads.
// Per tap k (9): stage w[k][64c][64o] in LDS; sample 64px x 64c into LDS;
// GEMM: thread (pg = t&15, og = t>>4) computes 4 outs x 4 pixels.
// Thread's pixels: {2pg, 2pg+1, 2pg+32, 2pg+33}.
#define SST 66   // s_tile stride (floats): banks (2c+2pg)%32 conflict-free reads
#define WST 68   // wlds stride
__global__ __launch_bounds__(256) void dcn_main(
    const float* __restrict__ xt, const float* __restrict__ off_pix,
    const float* __restrict__ wT, const float* __restrict__ bias,
    float* __restrict__ out) {
  __shared__ __align__(16) float coef[576 * 8];     // [p*9+k][w00,w01,w10,w11,i00,i01,i10,i11]
  __shared__ __align__(16) float s_tile[64 * SST];  // [c][pixel]
  __shared__ __align__(16) float wlds[64 * WST];    // [c][o]

  int blk = blockIdx.x;
  int wchunk = blk & 1;
  int h = (blk >> 1) & 127;
  int b = blk >> 8;
  int w0 = wchunk * 64;
  int tid = threadIdx.x;
  int lane = tid & 63;
  int wave = tid >> 6;

  const float* xbase = xt + (size_t)b * (128 * 128 * 64);
  const float* offbase = off_pix + (size_t)((b * 128 + h) * 128 + w0) * 18;

  // ---- coef precompute (once per block, all 64px x 9 taps) ----
  for (int it = tid; it < 576; it += 256) {
    int p = it / 9, k = it - p * 9;
    int ky = k / 3, kx = k - ky * 3;
    float2 o2 = *reinterpret_cast<const float2*>(offbase + p * 18 + 2 * k);
    float yf = (float)(h + ky - 1) + o2.x;
    float xf = (float)(w0 + p + kx - 1) + o2.y;
    float y0f = floorf(yf), x0f = floorf(xf);
    float wy = yf - y0f, wx = xf - x0f;
    int y0 = (int)y0f, x0 = (int)x0f;
    int y1 = y0 + 1, x1 = x0 + 1;
    float w00 = (1.f - wy) * (1.f - wx);
    float w01 = (1.f - wy) * wx;
    float w10 = wy * (1.f - wx);
    float w11 = wy * wx;
    bool vy0 = (unsigned)y0 < 128u, vy1 = (unsigned)y1 < 128u;
    bool vx0 = (unsigned)x0 < 128u, vx1 = (unsigned)x1 < 128u;
    if (!(vy0 && vx0)) w00 = 0.f;
    if (!(vy0 && vx1)) w01 = 0.f;
    if (!(vy1 && vx0)) w10 = 0.f;
    if (!(vy1 && vx1)) w11 = 0.f;
    int y0c = min(max(y0, 0), 127), y1c = min(max(y1, 0), 127);
    int x0c = min(max(x0, 0), 127), x1c = min(max(x1, 0), 127);
    float* cp = &coef[it * 8];
    *reinterpret_cast<float4*>(cp) = make_float4(w00, w01, w10, w11);
    *reinterpret_cast<int4*>(cp + 4) =
        make_int4((y0c * 128 + x0c) * 64, (y0c * 128 + x1c) * 64,
                  (y1c * 128 + x0c) * 64, (y1c * 128 + x1c) * 64);
  }

  int pg = tid & 15, og = tid >> 4;
  float acc[4][4];
#pragma unroll
  for (int i = 0; i < 4; i++)
#pragma unroll
    for (int j = 0; j < 4; j++) acc[i][j] = 0.f;

  __syncthreads();

#pragma unroll 1
  for (int k = 0; k < 9; k++) {
    // stage tap-k weights: wlds[c][o] = wT[k][c][o]
    const float* wk = wT + k * 4096;
#pragma unroll
    for (int r = 0; r < 16; r++) {
      int idx = tid + r * 256;
      wlds[(idx >> 6) * WST + (idx & 63)] = wk[idx];
    }
    // sample: this wave does pixels wave*16..+15, lanes = channels
#pragma unroll 1
    for (int i = 0; i < 16; i++) {
      int p = wave * 16 + i;
      const float* cp = &coef[(p * 9 + k) * 8];
      float4 cw = *reinterpret_cast<const float4*>(cp);
      int4 ci = *reinterpret_cast<const int4*>(cp + 4);
      float v00 = xbase[ci.x + lane];
      float v01 = xbase[ci.y + lane];
      float v10 = xbase[ci.z + lane];
      float v11 = xbase[ci.w + lane];
      s_tile[lane * SST + p] = cw.x * v00 + cw.y * v01 + cw.z * v10 + cw.w * v11;
    }
    __syncthreads();
    // GEMM over c for this tap
#pragma unroll 4
    for (int c = 0; c < 64; c++) {
      float2 sa = *reinterpret_cast<const float2*>(&s_tile[c * SST + 2 * pg]);
      float2 sb = *reinterpret_cast<const float2*>(&s_tile[c * SST + 2 * pg + 32]);
      float4 wv = *reinterpret_cast<const float4*>(&wlds[c * WST + og * 4]);
      acc[0][0] += wv.x * sa.x; acc[0][1] += wv.x * sa.y; acc[0][2] += wv.x * sb.x; acc[0][3] += wv.x * sb.y;
      acc[1][0] += wv.y * sa.x; acc[1][1] += wv.y * sa.y; acc[1][2] += wv.y * sb.x; acc[1][3] += wv.y * sb.y;
      acc[2][0] += wv.z * sa.x; acc[2][1] += wv.z * sa.y; acc[2][2] += wv.z * sb.x; acc[2][3] += wv.z * sb.y;
      acc[3][0] += wv.w * sa.x; acc[3][1] += wv.w * sa.y; acc[3][2] += wv.w * sb.x; acc[3][3] += wv.w * sb.y;
    }
    __syncthreads();
  }

  // ---- store: out[b][o][h][w0 + pixel] ----
  int o0 = og * 4;
  size_t outb = ((size_t)(b * 64 + o0)) * 16384 + h * 128 + w0;
#pragma unroll
  for (int i = 0; i < 4; i++) {
    float bv = bias[o0 + i];
    float2 r01 = make_float2(acc[i][0] + bv, acc[i][1] + bv);
    float2 r23 = make_float2(acc[i][2] + bv, acc[i][3] + bv);
    *reinterpret_cast<float2*>(&out[outb + (size_t)i * 16384 + 2 * pg]) = r01;
    *reinterpret_cast<float2*>(&out[outb + (size_t)i * 16384 + 2 * pg + 32]) = r23;
  }
}

extern "C" void kernel_launch(void* const* d_in, const int* in_sizes, int n_in,
                              void* d_out, int out_size, void* d_ws, size_t ws_size,
                              hipStream_t stream) {
  const float* x     = (const float*)d_in[0];
  const float* w_off = (const float*)d_in[1];
  const float* b_off = (const float*)d_in[2];
  const float* w     = (const float*)d_in[3];
  const float* b     = (const float*)d_in[4];
  float* out = (float*)d_out;
  float* ws = (float*)d_ws;

  float* wT      = ws;
  float* w_offT  = ws + 36864;
  float* xt      = ws + 65536;
  float* off_pix = ws + 4259840;

  prep_weights<<<64, 256, 0, stream>>>(w, w_off, wT, w_offT);
  transpose_x<<<1024, 256, 0, stream>>>(x, xt);
  offset_conv<<<256, 256, 0, stream>>>(xt, w_offT, b_off, off_pix);
  dcn_main<<<1024, 256, 0, stream>>>(xt, off_pix, wT, b, out);
}

// Round 3
// 199.453 us; speedup vs baseline: 2.3264x; 1.1991x over previous
//
#include <hip/hip_runtime.h>

// Deformable conv v1 fwd: B=4, C=64, H=W=128, K=3, O=64, fp32 in/out.
// Strategy: bf16 hi/lo split MFMA (3 products, drop lo*lo) for both convs.
//
// ws layout (bytes):
//   [0)         whi   u16[9][64][64]  (w:  [tap][o][c] hi plane)
//   [73728)     wlo   u16[9][64][64]
//   [147456)    wofh  u16[9][32][64]  (w_off padded 18->32 rows)
//   [184320)    wofl  u16[9][32][64]
//   [221184)    xt    f32[4][128][128][64]  (NHWC)
//   [16998400)  off_pix f32[4][128][128][18]
//   end 21716992 (~20.7 MB)

typedef unsigned short u16;
typedef __attribute__((ext_vector_type(8))) short bf16x8;
typedef __attribute__((ext_vector_type(4))) float f32x4;
#define MFMA __builtin_amdgcn_mfma_f32_16x16x32_bf16

__device__ __forceinline__ void bsplit(float v, u16& h, u16& l) {
  unsigned u = __float_as_uint(v);
  unsigned hb = (u + 0x7fffu + ((u >> 16) & 1u)) & 0xffff0000u;
  h = (u16)(hb >> 16);
  float r = v - __uint_as_float(hb);
  unsigned u2 = __float_as_uint(r);
  l = (u16)((u2 + 0x7fffu + ((u2 >> 16) & 1u)) >> 16);
}

__global__ __launch_bounds__(256) void prep_weights(
    const float* __restrict__ w, const float* __restrict__ w_off,
    u16* __restrict__ whi, u16* __restrict__ wlo,
    u16* __restrict__ wofh, u16* __restrict__ wofl) {
  int t = blockIdx.x * 256 + threadIdx.x;
  int stride = gridDim.x * 256;
  // whi/wlo[tap][o][c] from w[o*576 + c*9 + tap]
  for (int i = t; i < 9 * 64 * 64; i += stride) {
    int tap = i >> 12, o = (i >> 6) & 63, c = i & 63;
    u16 h, l;
    bsplit(w[o * 576 + c * 9 + tap], h, l);
    whi[i] = h; wlo[i] = l;
  }
  // wofh/wofl[tap][ch(32)][c], ch>=18 zero. w_off[ch*576 + c*9 + tap]
  for (int i = t; i < 9 * 32 * 64; i += stride) {
    int tap = i >> 11, ch = (i >> 6) & 31, c = i & 63;
    float v = (ch < 18) ? w_off[ch * 576 + c * 9 + tap] : 0.f;
    u16 h, l;
    bsplit(v, h, l);
    wofh[i] = h; wofl[i] = l;
  }
}

// NCHW -> NHWC fp32, LDS tile transpose. blk = b*256 + h*2 + wchunk
__global__ __launch_bounds__(256) void transpose_x(
    const float* __restrict__ x, float* __restrict__ xt) {
  __shared__ float tile[64][65];
  int blk = blockIdx.x;
  int wchunk = blk & 1;
  int h = (blk >> 1) & 127;
  int b = blk >> 8;
  int w0 = wchunk * 64;
  int r = threadIdx.x >> 6;
  int lane = threadIdx.x & 63;
#pragma unroll
  for (int i = 0; i < 16; i++) {
    int c = r + i * 4;
    tile[c][lane] = x[(((size_t)(b * 64 + c) * 128) + h) * 128 + w0 + lane];
  }
  __syncthreads();
#pragma unroll
  for (int i = 0; i < 16; i++) {
    int wi = r + i * 4;
    xt[(((size_t)(b * 128 + h) * 128) + w0 + wi) * 64 + lane] = tile[lane][wi];
  }
}

// Offset conv as MFMA GEMM: M=32(18 used), K=576, N=65536.
// Block: 256 px = 2 rows x 128 w. Wave wv: w in [32wv,32wv+32), both rows.
// p-tile pt: row=pt>>1, wbase=32wv+16(pt&1). B-frags from xt fp32, split on the fly.
__global__ __launch_bounds__(256) void offset_conv(
    const float* __restrict__ xt, const u16* __restrict__ wofh,
    const u16* __restrict__ wofl, const float* __restrict__ b_off,
    float* __restrict__ off_pix) {
  int blk = blockIdx.x;            // 256 = b*64 + hp
  int hp = blk & 63, b = blk >> 6;
  int h0 = hp * 2;
  int lane = threadIdx.x & 63, wv = threadIdx.x >> 6;
  int lm = lane & 15, lg = lane >> 4;
  const float* xb = xt + (size_t)b * (128 * 128 * 64);

  f32x4 acc[4][2];
#pragma unroll
  for (int i = 0; i < 4; i++)
#pragma unroll
    for (int j = 0; j < 2; j++) acc[i][j] = (f32x4)0.f;

#pragma unroll 1
  for (int tap = 0; tap < 9; tap++) {
    int ky = tap / 3, kx = tap - ky * 3;
#pragma unroll
    for (int kc = 0; kc < 2; kc++) {
      const u16* ah = wofh + tap * 2048 + lm * 64 + kc * 32 + lg * 8;
      const u16* al = wofl + tap * 2048 + lm * 64 + kc * 32 + lg * 8;
      bf16x8 a0h = *(const bf16x8*)ah;
      bf16x8 a0l = *(const bf16x8*)al;
      bf16x8 a1h = *(const bf16x8*)(ah + 1024);
      bf16x8 a1l = *(const bf16x8*)(al + 1024);
#pragma unroll
      for (int pt = 0; pt < 4; pt++) {
        int y = h0 + (pt >> 1) + ky - 1;
        if ((unsigned)y >= 128u) continue;       // wave-uniform
        int xx = wv * 32 + (pt & 1) * 16 + lm + kx - 1;
        bool valid = (unsigned)xx < 128u;
        int xc = min(max(xx, 0), 127);
        const float* xp = xb + ((size_t)(y * 128 + xc)) * 64 + kc * 32 + lg * 8;
        float4 xa = *(const float4*)xp;
        float4 xc4 = *(const float4*)(xp + 4);
        if (!valid) { xa = make_float4(0, 0, 0, 0); xc4 = make_float4(0, 0, 0, 0); }
        bf16x8 bh, bl;
        u16 h, l;
        bsplit(xa.x, h, l); bh[0] = h; bl[0] = l;
        bsplit(xa.y, h, l); bh[1] = h; bl[1] = l;
        bsplit(xa.z, h, l); bh[2] = h; bl[2] = l;
        bsplit(xa.w, h, l); bh[3] = h; bl[3] = l;
        bsplit(xc4.x, h, l); bh[4] = h; bl[4] = l;
        bsplit(xc4.y, h, l); bh[5] = h; bl[5] = l;
        bsplit(xc4.z, h, l); bh[6] = h; bl[6] = l;
        bsplit(xc4.w, h, l); bh[7] = h; bl[7] = l;
        acc[pt][0] = MFMA(a0h, bh, acc[pt][0], 0, 0, 0);
        acc[pt][0] = MFMA(a0h, bl, acc[pt][0], 0, 0, 0);
        acc[pt][0] = MFMA(a0l, bh, acc[pt][0], 0, 0, 0);
        acc[pt][1] = MFMA(a1h, bh, acc[pt][1], 0, 0, 0);
        acc[pt][1] = MFMA(a1h, bl, acc[pt][1], 0, 0, 0);
        acc[pt][1] = MFMA(a1l, bh, acc[pt][1], 0, 0, 0);
      }
    }
  }

  float4 bo = *(const float4*)(b_off + 4 * lg);
  float b16 = b_off[16], b17 = b_off[17];
#pragma unroll
  for (int pt = 0; pt < 4; pt++) {
    int y = h0 + (pt >> 1);
    int wc = wv * 32 + (pt & 1) * 16 + lm;
    size_t base = ((size_t)((b * 128 + y) * 128) + wc) * 18;
    float2 s0 = make_float2(acc[pt][0][0] + bo.x, acc[pt][0][1] + bo.y);
    float2 s1 = make_float2(acc[pt][0][2] + bo.z, acc[pt][0][3] + bo.w);
    *(float2*)(off_pix + base + 4 * lg) = s0;
    *(float2*)(off_pix + base + 4 * lg + 2) = s1;
    if (lg == 0) {
      float2 s2 = make_float2(acc[pt][1][0] + b16, acc[pt][1][1] + b17);
      *(float2*)(off_pix + base + 16) = s2;
    }
  }
}

// Fused bilinear sample + bf16-split MFMA GEMM.
// Block: 64 px of one row (blk = b*256 + h*2 + wc). Per tap: sample 64px x 64c
// -> swizzled LDS bf16 planes; 4 waves each own o-range 16*wave, all 64 px.
#define SWZ(p, byt) ((byt) ^ (((p) & 7) << 4))
__global__ __launch_bounds__(256) void dcn_main(
    const float* __restrict__ xt, const float* __restrict__ off_pix,
    const u16* __restrict__ whi, const u16* __restrict__ wlo,
    const float* __restrict__ bias, float* __restrict__ out) {
  __shared__ __align__(16) float coef[576 * 8];   // [p*9+k][w00..w11, i00..i11]
  __shared__ __align__(16) u16 shi[64 * 64];      // [p][c] bf16 hi, XOR-swizzled
  __shared__ __align__(16) u16 slo[64 * 64];

  int blk = blockIdx.x;
  int wc = blk & 1, h = (blk >> 1) & 127, b = blk >> 8;
  int w0 = wc * 64;
  int tid = threadIdx.x, lane = tid & 63, wave = tid >> 6;
  int lm = lane & 15, lg = lane >> 4;
  const float* xbase = xt + (size_t)b * (128 * 128 * 64);
  const float* offbase = off_pix + (size_t)((b * 128 + h) * 128 + w0) * 18;

  // coef precompute: 64 px x 9 taps
  for (int it = tid; it < 576; it += 256) {
    int p = it / 9, k = it - p * 9;
    int ky = k / 3, kx = k - ky * 3;
    float2 o2 = *reinterpret_cast<const float2*>(offbase + p * 18 + 2 * k);
    float yf = (float)(h + ky - 1) + o2.x;
    float xf = (float)(w0 + p + kx - 1) + o2.y;
    float y0f = floorf(yf), x0f = floorf(xf);
    float wy = yf - y0f, wx = xf - x0f;
    int y0 = (int)y0f, x0 = (int)x0f;
    int y1 = y0 + 1, x1 = x0 + 1;
    float w00 = (1.f - wy) * (1.f - wx);
    float w01 = (1.f - wy) * wx;
    float w10 = wy * (1.f - wx);
    float w11 = wy * wx;
    bool vy0 = (unsigned)y0 < 128u, vy1 = (unsigned)y1 < 128u;
    bool vx0 = (unsigned)x0 < 128u, vx1 = (unsigned)x1 < 128u;
    if (!(vy0 && vx0)) w00 = 0.f;
    if (!(vy0 && vx1)) w01 = 0.f;
    if (!(vy1 && vx0)) w10 = 0.f;
    if (!(vy1 && vx1)) w11 = 0.f;
    int y0c = min(max(y0, 0), 127), y1c = min(max(y1, 0), 127);
    int x0c = min(max(x0, 0), 127), x1c = min(max(x1, 0), 127);
    float* cp = &coef[it * 8];
    *reinterpret_cast<float4*>(cp) = make_float4(w00, w01, w10, w11);
    *reinterpret_cast<int4*>(cp + 4) =
        make_int4((y0c * 128 + x0c) * 64, (y0c * 128 + x1c) * 64,
                  (y1c * 128 + x0c) * 64, (y1c * 128 + x1c) * 64);
  }

  f32x4 acc[4];
#pragma unroll
  for (int i = 0; i < 4; i++) acc[i] = (f32x4)0.f;

  __syncthreads();

#pragma unroll 1
  for (int tap = 0; tap < 9; tap++) {
    // ---- sample 16 px per wave, lanes = channels ----
#pragma unroll 4
    for (int i = 0; i < 16; i++) {
      int p = wave * 16 + i;
      const float* cp = &coef[(p * 9 + tap) * 8];
      float4 cw = *reinterpret_cast<const float4*>(cp);
      int4 ci = *reinterpret_cast<const int4*>(cp + 4);
      float v = cw.x * xbase[ci.x + lane] + cw.y * xbase[ci.y + lane] +
                cw.z * xbase[ci.z + lane] + cw.w * xbase[ci.w + lane];
      u16 hb, lb;
      bsplit(v, hb, lb);
      int byt = SWZ(p, p * 128 + lane * 2);
      *(u16*)((char*)shi + byt) = hb;
      *(u16*)((char*)slo + byt) = lb;
    }
    __syncthreads();

    // ---- A frags (global, per tap) ----
    const u16* wh = whi + tap * 4096 + (wave * 16 + lm) * 64 + lg * 8;
    const u16* wl = wlo + tap * 4096 + (wave * 16 + lm) * 64 + lg * 8;
    bf16x8 ah0 = *(const bf16x8*)wh;
    bf16x8 ah1 = *(const bf16x8*)(wh + 32);
    bf16x8 al0 = *(const bf16x8*)wl;
    bf16x8 al1 = *(const bf16x8*)(wl + 32);

    // ---- MFMA: 4 p-tiles x 2 kc x 3 products ----
#pragma unroll
    for (int pt = 0; pt < 4; pt++) {
      int p = pt * 16 + lm;
      int byt0 = SWZ(p, p * 128 + lg * 16);
      int byt1 = SWZ(p, p * 128 + 64 + lg * 16);
      bf16x8 bh0 = *(const bf16x8*)((char*)shi + byt0);
      bf16x8 bl0 = *(const bf16x8*)((char*)slo + byt0);
      bf16x8 bh1 = *(const bf16x8*)((char*)shi + byt1);
      bf16x8 bl1 = *(const bf16x8*)((char*)slo + byt1);
      acc[pt] = MFMA(ah0, bh0, acc[pt], 0, 0, 0);
      acc[pt] = MFMA(ah0, bl0, acc[pt], 0, 0, 0);
      acc[pt] = MFMA(al0, bh0, acc[pt], 0, 0, 0);
      acc[pt] = MFMA(ah1, bh1, acc[pt], 0, 0, 0);
      acc[pt] = MFMA(ah1, bl1, acc[pt], 0, 0, 0);
      acc[pt] = MFMA(al1, bh1, acc[pt], 0, 0, 0);
    }
    __syncthreads();
  }

  // ---- store: lane holds D[o = wave*16 + 4*lg + r][p = pt*16 + lm] ----
  float4 bv = *(const float4*)(bias + wave * 16 + 4 * lg);
#pragma unroll
  for (int pt = 0; pt < 4; pt++) {
#pragma unroll
    for (int r = 0; r < 4; r++) {
      int o = wave * 16 + 4 * lg + r;
      float bb = (r == 0) ? bv.x : (r == 1) ? bv.y : (r == 2) ? bv.z : bv.w;
      out[((size_t)(b * 64 + o)) * 16384 + h * 128 + w0 + pt * 16 + lm] =
          acc[pt][r] + bb;
    }
  }
}

extern "C" void kernel_launch(void* const* d_in, const int* in_sizes, int n_in,
                              void* d_out, int out_size, void* d_ws, size_t ws_size,
                              hipStream_t stream) {
  const float* x     = (const float*)d_in[0];
  const float* w_off = (const float*)d_in[1];
  const float* b_off = (const float*)d_in[2];
  const float* w     = (const float*)d_in[3];
  const float* b     = (const float*)d_in[4];
  float* out = (float*)d_out;
  char* ws = (char*)d_ws;

  u16*   whi     = (u16*)(ws);
  u16*   wlo     = (u16*)(ws + 73728);
  u16*   wofh    = (u16*)(ws + 147456);
  u16*   wofl    = (u16*)(ws + 184320);
  float* xt      = (float*)(ws + 221184);
  float* off_pix = (float*)(ws + 16998400);

  prep_weights<<<64, 256, 0, stream>>>(w, w_off, whi, wlo, wofh, wofl);
  transpose_x<<<1024, 256, 0, stream>>>(x, xt);
  offset_conv<<<256, 256, 0, stream>>>(xt, wofh, wofl, b_off, off_pix);
  dcn_main<<<1024, 256, 0, stream>>>(xt, off_pix, whi, wlo, b, out);
}

// Round 9
// 174.112 us; speedup vs baseline: 2.6650x; 1.1455x over previous
//
#include <hip/hip_runtime.h>

// Deformable conv v1 fwd: B=4, C=64, H=W=128, K=3, O=64, fp32 in/out.
// bf16 hi/lo split MFMA (3 products). RECOVERY ROUND: R3-verbatim kernels;
// dcn_main adds ONLY (a) XCD chunked swizzle, (b) gather hoist within the
// R3 two-barrier single-buffer tap loop.
//
// ws layout (bytes):
//   [0)        whi   u16[9][64][64]   (w: [tap][o][c] hi plane)
//   [73728)    wlo   u16[9][64][64]
//   [147456)   wofh  u16[9][32][64]   (w_off padded 18->32 rows, [tap][ch][c])
//   [184320)   wofl  u16[9][32][64]
//   [221184)   xt    f32[4][128][128][64]  (NHWC)
//   [16998400) off_pix f32[4][128][128][18]
//   end 21716992 (~20.7 MB)

typedef unsigned short u16;
typedef __attribute__((ext_vector_type(8))) short bf16x8;
typedef __attribute__((ext_vector_type(4))) float f32x4;
#define MFMA __builtin_amdgcn_mfma_f32_16x16x32_bf16

__device__ __forceinline__ void bsplit(float v, u16& h, u16& l) {
  unsigned u = __float_as_uint(v);
  unsigned hb = (u + 0x7fffu + ((u >> 16) & 1u)) & 0xffff0000u;
  h = (u16)(hb >> 16);
  float r = v - __uint_as_float(hb);
  unsigned u2 = __float_as_uint(r);
  l = (u16)((u2 + 0x7fffu + ((u2 >> 16) & 1u)) >> 16);
}

__global__ __launch_bounds__(256) void prep_weights(
    const float* __restrict__ w, const float* __restrict__ w_off,
    u16* __restrict__ whi, u16* __restrict__ wlo,
    u16* __restrict__ wofh, u16* __restrict__ wofl) {
  int t = blockIdx.x * 256 + threadIdx.x;
  int stride = gridDim.x * 256;
  for (int i = t; i < 9 * 64 * 64; i += stride) {
    int tap = i >> 12, o = (i >> 6) & 63, c = i & 63;
    u16 h, l;
    bsplit(w[o * 576 + c * 9 + tap], h, l);
    whi[i] = h; wlo[i] = l;
  }
  for (int i = t; i < 9 * 32 * 64; i += stride) {
    int tap = i >> 11, ch = (i >> 6) & 31, c = i & 63;
    float v = (ch < 18) ? w_off[ch * 576 + c * 9 + tap] : 0.f;
    u16 h, l;
    bsplit(v, h, l);
    wofh[i] = h; wofl[i] = l;
  }
}

// NCHW -> NHWC fp32, LDS tile transpose. blk = b*256 + h*2 + wchunk
__global__ __launch_bounds__(256) void transpose_x(
    const float* __restrict__ x, float* __restrict__ xt) {
  __shared__ float tile[64][65];
  int blk = blockIdx.x;
  int wchunk = blk & 1;
  int h = (blk >> 1) & 127;
  int b = blk >> 8;
  int w0 = wchunk * 64;
  int r = threadIdx.x >> 6;
  int lane = threadIdx.x & 63;
#pragma unroll
  for (int i = 0; i < 16; i++) {
    int c = r + i * 4;
    tile[c][lane] = x[(((size_t)(b * 64 + c) * 128) + h) * 128 + w0 + lane];
  }
  __syncthreads();
#pragma unroll
  for (int i = 0; i < 16; i++) {
    int wi = r + i * 4;
    xt[(((size_t)(b * 128 + h) * 128) + w0 + wi) * 64 + lane] = tile[lane][wi];
  }
}

// Offset conv as MFMA GEMM (Round-3 verbatim, known good).
__global__ __launch_bounds__(256) void offset_conv(
    const float* __restrict__ xt, const u16* __restrict__ wofh,
    const u16* __restrict__ wofl, const float* __restrict__ b_off,
    float* __restrict__ off_pix) {
  int blk = blockIdx.x;            // 256 = b*64 + hp
  int hp = blk & 63, b = blk >> 6;
  int h0 = hp * 2;
  int lane = threadIdx.x & 63, wv = threadIdx.x >> 6;
  int lm = lane & 15, lg = lane >> 4;
  const float* xb = xt + (size_t)b * (128 * 128 * 64);

  f32x4 acc[4][2];
#pragma unroll
  for (int i = 0; i < 4; i++)
#pragma unroll
    for (int j = 0; j < 2; j++) acc[i][j] = (f32x4)0.f;

#pragma unroll 1
  for (int tap = 0; tap < 9; tap++) {
    int ky = tap / 3, kx = tap - ky * 3;
#pragma unroll
    for (int kc = 0; kc < 2; kc++) {
      const u16* ah = wofh + tap * 2048 + lm * 64 + kc * 32 + lg * 8;
      const u16* al = wofl + tap * 2048 + lm * 64 + kc * 32 + lg * 8;
      bf16x8 a0h = *(const bf16x8*)ah;
      bf16x8 a0l = *(const bf16x8*)al;
      bf16x8 a1h = *(const bf16x8*)(ah + 1024);
      bf16x8 a1l = *(const bf16x8*)(al + 1024);
#pragma unroll
      for (int pt = 0; pt < 4; pt++) {
        int y = h0 + (pt >> 1) + ky - 1;
        if ((unsigned)y >= 128u) continue;       // wave-uniform
        int xx = wv * 32 + (pt & 1) * 16 + lm + kx - 1;
        bool valid = (unsigned)xx < 128u;
        int xc = min(max(xx, 0), 127);
        const float* xp = xb + ((size_t)(y * 128 + xc)) * 64 + kc * 32 + lg * 8;
        float4 xa = *(const float4*)xp;
        float4 xc4 = *(const float4*)(xp + 4);
        if (!valid) { xa = make_float4(0, 0, 0, 0); xc4 = make_float4(0, 0, 0, 0); }
        bf16x8 bh, bl;
        u16 h, l;
        bsplit(xa.x, h, l); bh[0] = h; bl[0] = l;
        bsplit(xa.y, h, l); bh[1] = h; bl[1] = l;
        bsplit(xa.z, h, l); bh[2] = h; bl[2] = l;
        bsplit(xa.w, h, l); bh[3] = h; bl[3] = l;
        bsplit(xc4.x, h, l); bh[4] = h; bl[4] = l;
        bsplit(xc4.y, h, l); bh[5] = h; bl[5] = l;
        bsplit(xc4.z, h, l); bh[6] = h; bl[6] = l;
        bsplit(xc4.w, h, l); bh[7] = h; bl[7] = l;
        acc[pt][0] = MFMA(a0h, bh, acc[pt][0], 0, 0, 0);
        acc[pt][0] = MFMA(a0h, bl, acc[pt][0], 0, 0, 0);
        acc[pt][0] = MFMA(a0l, bh, acc[pt][0], 0, 0, 0);
        acc[pt][1] = MFMA(a1h, bh, acc[pt][1], 0, 0, 0);
        acc[pt][1] = MFMA(a1h, bl, acc[pt][1], 0, 0, 0);
        acc[pt][1] = MFMA(a1l, bh, acc[pt][1], 0, 0, 0);
      }
    }
  }

  float4 bo = *(const float4*)(b_off + 4 * lg);
  float b16 = b_off[16], b17 = b_off[17];
#pragma unroll
  for (int pt = 0; pt < 4; pt++) {
    int y = h0 + (pt >> 1);
    int wc = wv * 32 + (pt & 1) * 16 + lm;
    size_t base = ((size_t)((b * 128 + y) * 128) + wc) * 18;
    float2 s0 = make_float2(acc[pt][0][0] + bo.x, acc[pt][0][1] + bo.y);
    float2 s1 = make_float2(acc[pt][0][2] + bo.z, acc[pt][0][3] + bo.w);
    *(float2*)(off_pix + base + 4 * lg) = s0;
    *(float2*)(off_pix + base + 4 * lg + 2) = s1;
    if (lg == 0) {
      float2 s2 = make_float2(acc[pt][1][0] + b16, acc[pt][1][1] + b17);
      *(float2*)(off_pix + base + 16) = s2;
    }
  }
}

// Bilinear sample + bf16-split MFMA GEMM. R3 two-barrier single-buffer
// structure; adds XCD swizzle + gather hoist (loads for tap t+1 issued
// between barrier-1 and MFMA of tap t).
#define SWZ(p, byt) ((byt) ^ (((p) & 7) << 4))
__global__ __launch_bounds__(256) void dcn_main(
    const float* __restrict__ xt, const float* __restrict__ off_pix,
    const u16* __restrict__ whi, const u16* __restrict__ wlo,
    const float* __restrict__ bias, float* __restrict__ out) {
  __shared__ __align__(16) float cw_lds[576][4];   // bilinear weights
  __shared__ __align__(16) int   ci_lds[576][4];   // corner float-index offsets
  __shared__ __align__(16) u16 shi[64 * 64];       // [p][c] bf16 hi, XOR-swizzled
  __shared__ __align__(16) u16 slo[64 * 64];

  int blk = blockIdx.x;
  int wg = ((blk & 7) << 7) | (blk >> 3);          // bijective XCD chunk swizzle
  int wc = wg & 1, h = (wg >> 1) & 127, b = wg >> 8;
  int w0 = wc * 64;
  int tid = threadIdx.x, lane = tid & 63, wave = tid >> 6;
  int lm = lane & 15, lg = lane >> 4;
  const float* xbase = xt + (size_t)b * (128 * 128 * 64);
  const float* offbase = off_pix + (size_t)((b * 128 + h) * 128 + w0) * 18;

  // ---- coef precompute: 64 px x 9 taps (R3 math, element offsets) ----
#pragma unroll 1
  for (int it = tid; it < 576; it += 256) {
    int p = it / 9, k = it - p * 9;
    int ky = k / 3, kx = k - ky * 3;
    float2 o2 = *reinterpret_cast<const float2*>(offbase + p * 18 + 2 * k);
    float yf = (float)(h + ky - 1) + o2.x;
    float xf = (float)(w0 + p + kx - 1) + o2.y;
    float y0f = floorf(yf), x0f = floorf(xf);
    float wy = yf - y0f, wx = xf - x0f;
    int y0 = (int)y0f, x0 = (int)x0f;
    int y1 = y0 + 1, x1 = x0 + 1;
    float w00 = (1.f - wy) * (1.f - wx);
    float w01 = (1.f - wy) * wx;
    float w10 = wy * (1.f - wx);
    float w11 = wy * wx;
    bool vy0 = (unsigned)y0 < 128u, vy1 = (unsigned)y1 < 128u;
    bool vx0 = (unsigned)x0 < 128u, vx1 = (unsigned)x1 < 128u;
    if (!(vy0 && vx0)) w00 = 0.f;
    if (!(vy0 && vx1)) w01 = 0.f;
    if (!(vy1 && vx0)) w10 = 0.f;
    if (!(vy1 && vx1)) w11 = 0.f;
    int y0c = min(max(y0, 0), 127), y1c = min(max(y1, 0), 127);
    int x0c = min(max(x0, 0), 127), x1c = min(max(x1, 0), 127);
    *(float4*)cw_lds[it] = make_float4(w00, w01, w10, w11);
    *(int4*)ci_lds[it] =
        make_int4((y0c * 128 + x0c) * 64, (y0c * 128 + x1c) * 64,
                  (y1c * 128 + x0c) * 64, (y1c * 128 + x1c) * 64);
  }
  __syncthreads();

  f32x4 acc[4];
#pragma unroll
  for (int i = 0; i < 4; i++) acc[i] = (f32x4)0.f;

  float g[16][4];

  // prefetch tap 0 gathers
#pragma unroll
  for (int i = 0; i < 16; i++) {
    int4 ci = *(const int4*)ci_lds[(wave * 16 + i) * 9 + 0];
    g[i][0] = xbase[ci.x + lane];
    g[i][1] = xbase[ci.y + lane];
    g[i][2] = xbase[ci.z + lane];
    g[i][3] = xbase[ci.w + lane];
  }

#pragma unroll 1
  for (int tap = 0; tap < 9; tap++) {
    // ---- combine tap's gathers -> LDS (single buffer, as R3) ----
#pragma unroll
    for (int i = 0; i < 16; i++) {
      int p = wave * 16 + i;
      float4 cwv = *(const float4*)cw_lds[p * 9 + tap];
      float v = cwv.x * g[i][0] + cwv.y * g[i][1] +
                cwv.z * g[i][2] + cwv.w * g[i][3];
      u16 hh, ll;
      bsplit(v, hh, ll);
      int byt = SWZ(p, p * 128 + lane * 2);
      *(u16*)((char*)shi + byt) = hh;
      *(u16*)((char*)slo + byt) = ll;
    }
    __syncthreads();                 // B1: tile visible

    // ---- hoisted gathers for tap+1 (registers only, overlap with MFMA) ----
    if (tap < 8) {
#pragma unroll
      for (int i = 0; i < 16; i++) {
        int4 ci = *(const int4*)ci_lds[(wave * 16 + i) * 9 + tap + 1];
        g[i][0] = xbase[ci.x + lane];
        g[i][1] = xbase[ci.y + lane];
        g[i][2] = xbase[ci.z + lane];
        g[i][3] = xbase[ci.w + lane];
      }
    }

    // ---- MFMA for this tap (R3 verbatim) ----
    const u16* wh = whi + tap * 4096 + (wave * 16 + lm) * 64 + lg * 8;
    const u16* wl = wlo + tap * 4096 + (wave * 16 + lm) * 64 + lg * 8;
    bf16x8 ah0 = *(const bf16x8*)wh;
    bf16x8 ah1 = *(const bf16x8*)(wh + 32);
    bf16x8 al0 = *(const bf16x8*)wl;
    bf16x8 al1 = *(const bf16x8*)(wl + 32);
#pragma unroll
    for (int pt = 0; pt < 4; pt++) {
      int p = pt * 16 + lm;
      int byt0 = SWZ(p, p * 128 + lg * 16);
      int byt1 = SWZ(p, p * 128 + 64 + lg * 16);
      bf16x8 bh0 = *(const bf16x8*)((char*)shi + byt0);
      bf16x8 bl0 = *(const bf16x8*)((char*)slo + byt0);
      bf16x8 bh1 = *(const bf16x8*)((char*)shi + byt1);
      bf16x8 bl1 = *(const bf16x8*)((char*)slo + byt1);
      acc[pt] = MFMA(ah0, bh0, acc[pt], 0, 0, 0);
      acc[pt] = MFMA(ah0, bl0, acc[pt], 0, 0, 0);
      acc[pt] = MFMA(al0, bh0, acc[pt], 0, 0, 0);
      acc[pt] = MFMA(ah1, bh1, acc[pt], 0, 0, 0);
      acc[pt] = MFMA(ah1, bl1, acc[pt], 0, 0, 0);
      acc[pt] = MFMA(al1, bh1, acc[pt], 0, 0, 0);
    }
    __syncthreads();                 // B2: reads done before next combine
  }

  // ---- store: lane holds D[o = wave*16 + 4*lg + r][p = pt*16 + lm] ----
  float4 bv = *(const float4*)(bias + wave * 16 + 4 * lg);
  size_t ob = ((size_t)(b * 64 + wave * 16 + 4 * lg)) * 16384 + h * 128 + w0;
#pragma unroll
  for (int pt = 0; pt < 4; pt++) {
#pragma unroll
    for (int r = 0; r < 4; r++) {
      float bb = (r == 0) ? bv.x : (r == 1) ? bv.y : (r == 2) ? bv.z : bv.w;
      out[ob + (size_t)r * 16384 + pt * 16 + lm] = acc[pt][r] + bb;
    }
  }
}

extern "C" void kernel_launch(void* const* d_in, const int* in_sizes, int n_in,
                              void* d_out, int out_size, void* d_ws, size_t ws_size,
                              hipStream_t stream) {
  const float* x     = (const float*)d_in[0];
  const float* w_off = (const float*)d_in[1];
  const float* b_off = (const float*)d_in[2];
  const float* w     = (const float*)d_in[3];
  const float* b     = (const float*)d_in[4];
  float* out = (float*)d_out;
  char* ws = (char*)d_ws;

  u16*   whi     = (u16*)(ws);
  u16*   wlo     = (u16*)(ws + 73728);
  u16*   wofh    = (u16*)(ws + 147456);
  u16*   wofl    = (u16*)(ws + 184320);
  float* xtw     = (float*)(ws + 221184);
  float* off_pix = (float*)(ws + 16998400);

  prep_weights<<<64, 256, 0, stream>>>(w, w_off, whi, wlo, wofh, wofl);
  transpose_x<<<1024, 256, 0, stream>>>(x, xtw);
  offset_conv<<<256, 256, 0, stream>>>(xtw, wofh, wofl, b_off, off_pix);
  dcn_main<<<1024, 256, 0, stream>>>(xtw, off_pix, whi, wlo, b, out);
}

// Round 10
// 169.062 us; speedup vs baseline: 2.7446x; 1.0299x over previous
//
#include <hip/hip_runtime.h>

// Deformable conv v1 fwd: B=4, C=64, H=W=128, K=3, O=64, fp32 in/out.
// bf16 split MFMA: A-side (weights) hi+lo planes, B-side (data) single RNE
// bf16 (error budget: threshold 8.4e-2, measured 1.6e-2 with full B-lo;
// dropping B-lo adds ~5e-3). dcn_main: XCD swizzle + gather hoist in the
// R3 two-barrier single-buffer tap loop (verified structure, R6=174us).
//
// ws layout (bytes):
//   [0)        whi   u16[9][64][64]   (w: [tap][o][c] hi plane)
//   [73728)    wlo   u16[9][64][64]
//   [147456)   wofh  u16[9][32][64]   (w_off padded 18->32 rows, [tap][ch][c])
//   [184320)   wofl  u16[9][32][64]
//   [221184)   xt    f32[4][128][128][64]  (NHWC)
//   [16998400) off_pix f32[4][128][128][18]
//   end 21716992 (~20.7 MB)

typedef unsigned short u16;
typedef __attribute__((ext_vector_type(8))) short bf16x8;
typedef __attribute__((ext_vector_type(4))) float f32x4;
#define MFMA __builtin_amdgcn_mfma_f32_16x16x32_bf16

__device__ __forceinline__ void bsplit(float v, u16& h, u16& l) {
  unsigned u = __float_as_uint(v);
  unsigned hb = (u + 0x7fffu + ((u >> 16) & 1u)) & 0xffff0000u;
  h = (u16)(hb >> 16);
  float r = v - __uint_as_float(hb);
  unsigned u2 = __float_as_uint(r);
  l = (u16)((u2 + 0x7fffu + ((u2 >> 16) & 1u)) >> 16);
}

__device__ __forceinline__ u16 brnd(float v) {   // fp32 -> bf16 RNE
  unsigned u = __float_as_uint(v);
  return (u16)((u + 0x7fffu + ((u >> 16) & 1u)) >> 16);
}

__global__ __launch_bounds__(256) void prep_weights(
    const float* __restrict__ w, const float* __restrict__ w_off,
    u16* __restrict__ whi, u16* __restrict__ wlo,
    u16* __restrict__ wofh, u16* __restrict__ wofl) {
  int t = blockIdx.x * 256 + threadIdx.x;
  int stride = gridDim.x * 256;
  for (int i = t; i < 9 * 64 * 64; i += stride) {
    int tap = i >> 12, o = (i >> 6) & 63, c = i & 63;
    u16 h, l;
    bsplit(w[o * 576 + c * 9 + tap], h, l);
    whi[i] = h; wlo[i] = l;
  }
  for (int i = t; i < 9 * 32 * 64; i += stride) {
    int tap = i >> 11, ch = (i >> 6) & 31, c = i & 63;
    float v = (ch < 18) ? w_off[ch * 576 + c * 9 + tap] : 0.f;
    u16 h, l;
    bsplit(v, h, l);
    wofh[i] = h; wofl[i] = l;
  }
}

// NCHW -> NHWC fp32, LDS tile transpose. blk = b*256 + h*2 + wchunk
__global__ __launch_bounds__(256) void transpose_x(
    const float* __restrict__ x, float* __restrict__ xt) {
  __shared__ float tile[64][65];
  int blk = blockIdx.x;
  int wchunk = blk & 1;
  int h = (blk >> 1) & 127;
  int b = blk >> 8;
  int w0 = wchunk * 64;
  int r = threadIdx.x >> 6;
  int lane = threadIdx.x & 63;
#pragma unroll
  for (int i = 0; i < 16; i++) {
    int c = r + i * 4;
    tile[c][lane] = x[(((size_t)(b * 64 + c) * 128) + h) * 128 + w0 + lane];
  }
  __syncthreads();
#pragma unroll
  for (int i = 0; i < 16; i++) {
    int wi = r + i * 4;
    xt[(((size_t)(b * 128 + h) * 128) + w0 + wi) * 64 + lane] = tile[lane][wi];
  }
}

// Offset conv as MFMA GEMM. 512 blocks (1 row each, 2 blocks/CU).
// A = wof hi/lo planes, B = x as single RNE bf16 (4 MFMA per tap,kc).
__global__ __launch_bounds__(256) void offset_conv(
    const float* __restrict__ xt, const u16* __restrict__ wofh,
    const u16* __restrict__ wofl, const float* __restrict__ b_off,
    float* __restrict__ off_pix) {
  int blk = blockIdx.x;            // 512 = b*128 + h
  int h = blk & 127, b = blk >> 7;
  int lane = threadIdx.x & 63, wv = threadIdx.x >> 6;
  int lm = lane & 15, lg = lane >> 4;
  const float* xb = xt + (size_t)b * (128 * 128 * 64);

  f32x4 acc[2][2];
#pragma unroll
  for (int i = 0; i < 2; i++)
#pragma unroll
    for (int j = 0; j < 2; j++) acc[i][j] = (f32x4)0.f;

#pragma unroll 1
  for (int tap = 0; tap < 9; tap++) {
    int ky = tap / 3, kx = tap - ky * 3;
    int y = h + ky - 1;
    if ((unsigned)y >= 128u) continue;           // block-uniform
#pragma unroll
    for (int kc = 0; kc < 2; kc++) {
      const u16* ah = wofh + tap * 2048 + lm * 64 + kc * 32 + lg * 8;
      const u16* al = wofl + tap * 2048 + lm * 64 + kc * 32 + lg * 8;
      bf16x8 a0h = *(const bf16x8*)ah;
      bf16x8 a0l = *(const bf16x8*)al;
      bf16x8 a1h = *(const bf16x8*)(ah + 1024);
      bf16x8 a1l = *(const bf16x8*)(al + 1024);
#pragma unroll
      for (int pt = 0; pt < 2; pt++) {
        int xx = wv * 32 + pt * 16 + lm + kx - 1;
        bool valid = (unsigned)xx < 128u;
        int xc = min(max(xx, 0), 127);
        const float* xp = xb + ((size_t)(y * 128 + xc)) * 64 + kc * 32 + lg * 8;
        float4 xa = *(const float4*)xp;
        float4 xd = *(const float4*)(xp + 4);
        if (!valid) { xa = make_float4(0, 0, 0, 0); xd = make_float4(0, 0, 0, 0); }
        bf16x8 bh;
        bh[0] = brnd(xa.x); bh[1] = brnd(xa.y);
        bh[2] = brnd(xa.z); bh[3] = brnd(xa.w);
        bh[4] = brnd(xd.x); bh[5] = brnd(xd.y);
        bh[6] = brnd(xd.z); bh[7] = brnd(xd.w);
        acc[pt][0] = MFMA(a0h, bh, acc[pt][0], 0, 0, 0);
        acc[pt][0] = MFMA(a0l, bh, acc[pt][0], 0, 0, 0);
        acc[pt][1] = MFMA(a1h, bh, acc[pt][1], 0, 0, 0);
        acc[pt][1] = MFMA(a1l, bh, acc[pt][1], 0, 0, 0);
      }
    }
  }

  float4 bo = *(const float4*)(b_off + 4 * lg);
  float b16 = b_off[16], b17 = b_off[17];
#pragma unroll
  for (int pt = 0; pt < 2; pt++) {
    int wc = wv * 32 + pt * 16 + lm;
    size_t base = ((size_t)((b * 128 + h) * 128) + wc) * 18;
    float2 s0 = make_float2(acc[pt][0][0] + bo.x, acc[pt][0][1] + bo.y);
    float2 s1 = make_float2(acc[pt][0][2] + bo.z, acc[pt][0][3] + bo.w);
    *(float2*)(off_pix + base + 4 * lg) = s0;
    *(float2*)(off_pix + base + 4 * lg + 2) = s1;
    if (lg == 0) {
      float2 s2 = make_float2(acc[pt][1][0] + b16, acc[pt][1][1] + b17);
      *(float2*)(off_pix + base + 16) = s2;
    }
  }
}

// Bilinear sample + split MFMA GEMM. R6-verified structure (two barriers,
// single buffer, XCD swizzle, gather hoist). B-side single bf16 plane.
#define SWZ(p, byt) ((byt) ^ (((p) & 7) << 4))
__global__ __launch_bounds__(256) void dcn_main(
    const float* __restrict__ xt, const float* __restrict__ off_pix,
    const u16* __restrict__ whi, const u16* __restrict__ wlo,
    const float* __restrict__ bias, float* __restrict__ out) {
  __shared__ __align__(16) float cw_lds[576][4];   // bilinear weights
  __shared__ __align__(16) int   ci_lds[576][4];   // corner float-index offsets
  __shared__ __align__(16) u16 shi[64 * 64];       // [p][c] bf16, XOR-swizzled

  int blk = blockIdx.x;
  int wg = ((blk & 7) << 7) | (blk >> 3);          // bijective XCD chunk swizzle
  int wc = wg & 1, h = (wg >> 1) & 127, b = wg >> 8;
  int w0 = wc * 64;
  int tid = threadIdx.x, lane = tid & 63, wave = tid >> 6;
  int lm = lane & 15, lg = lane >> 4;
  const float* xbase = xt + (size_t)b * (128 * 128 * 64);
  const float* offbase = off_pix + (size_t)((b * 128 + h) * 128 + w0) * 18;

  // ---- coef precompute: 64 px x 9 taps ----
#pragma unroll 1
  for (int it = tid; it < 576; it += 256) {
    int p = it / 9, k = it - p * 9;
    int ky = k / 3, kx = k - ky * 3;
    float2 o2 = *reinterpret_cast<const float2*>(offbase + p * 18 + 2 * k);
    float yf = (float)(h + ky - 1) + o2.x;
    float xf = (float)(w0 + p + kx - 1) + o2.y;
    float y0f = floorf(yf), x0f = floorf(xf);
    float wy = yf - y0f, wx = xf - x0f;
    int y0 = (int)y0f, x0 = (int)x0f;
    int y1 = y0 + 1, x1 = x0 + 1;
    float w00 = (1.f - wy) * (1.f - wx);
    float w01 = (1.f - wy) * wx;
    float w10 = wy * (1.f - wx);
    float w11 = wy * wx;
    bool vy0 = (unsigned)y0 < 128u, vy1 = (unsigned)y1 < 128u;
    bool vx0 = (unsigned)x0 < 128u, vx1 = (unsigned)x1 < 128u;
    if (!(vy0 && vx0)) w00 = 0.f;
    if (!(vy0 && vx1)) w01 = 0.f;
    if (!(vy1 && vx0)) w10 = 0.f;
    if (!(vy1 && vx1)) w11 = 0.f;
    int y0c = min(max(y0, 0), 127), y1c = min(max(y1, 0), 127);
    int x0c = min(max(x0, 0), 127), x1c = min(max(x1, 0), 127);
    *(float4*)cw_lds[it] = make_float4(w00, w01, w10, w11);
    *(int4*)ci_lds[it] =
        make_int4((y0c * 128 + x0c) * 64, (y0c * 128 + x1c) * 64,
                  (y1c * 128 + x0c) * 64, (y1c * 128 + x1c) * 64);
  }
  __syncthreads();

  f32x4 acc[4];
#pragma unroll
  for (int i = 0; i < 4; i++) acc[i] = (f32x4)0.f;

  float g[16][4];

  // prefetch tap 0 gathers
#pragma unroll
  for (int i = 0; i < 16; i++) {
    int4 ci = *(const int4*)ci_lds[(wave * 16 + i) * 9 + 0];
    g[i][0] = xbase[ci.x + lane];
    g[i][1] = xbase[ci.y + lane];
    g[i][2] = xbase[ci.z + lane];
    g[i][3] = xbase[ci.w + lane];
  }

#pragma unroll 1
  for (int tap = 0; tap < 9; tap++) {
    // ---- combine tap's gathers -> LDS (single buffer) ----
#pragma unroll
    for (int i = 0; i < 16; i++) {
      int p = wave * 16 + i;
      float4 cwv = *(const float4*)cw_lds[p * 9 + tap];
      float v = cwv.x * g[i][0] + cwv.y * g[i][1] +
                cwv.z * g[i][2] + cwv.w * g[i][3];
      int byt = SWZ(p, p * 128 + lane * 2);
      *(u16*)((char*)shi + byt) = brnd(v);
    }
    __syncthreads();                 // B1: tile visible

    // ---- hoisted gathers for tap+1 (registers only, overlap with MFMA) ----
    if (tap < 8) {
#pragma unroll
      for (int i = 0; i < 16; i++) {
        int4 ci = *(const int4*)ci_lds[(wave * 16 + i) * 9 + tap + 1];
        g[i][0] = xbase[ci.x + lane];
        g[i][1] = xbase[ci.y + lane];
        g[i][2] = xbase[ci.z + lane];
        g[i][3] = xbase[ci.w + lane];
      }
    }

    // ---- MFMA for this tap: A hi/lo x B hi ----
    const u16* wh = whi + tap * 4096 + (wave * 16 + lm) * 64 + lg * 8;
    const u16* wl = wlo + tap * 4096 + (wave * 16 + lm) * 64 + lg * 8;
    bf16x8 ah0 = *(const bf16x8*)wh;
    bf16x8 ah1 = *(const bf16x8*)(wh + 32);
    bf16x8 al0 = *(const bf16x8*)wl;
    bf16x8 al1 = *(const bf16x8*)(wl + 32);
#pragma unroll
    for (int pt = 0; pt < 4; pt++) {
      int p = pt * 16 + lm;
      int byt0 = SWZ(p, p * 128 + lg * 16);
      int byt1 = SWZ(p, p * 128 + 64 + lg * 16);
      bf16x8 bh0 = *(const bf16x8*)((char*)shi + byt0);
      bf16x8 bh1 = *(const bf16x8*)((char*)shi + byt1);
      acc[pt] = MFMA(ah0, bh0, acc[pt], 0, 0, 0);
      acc[pt] = MFMA(al0, bh0, acc[pt], 0, 0, 0);
      acc[pt] = MFMA(ah1, bh1, acc[pt], 0, 0, 0);
      acc[pt] = MFMA(al1, bh1, acc[pt], 0, 0, 0);
    }
    __syncthreads();                 // B2: reads done before next combine
  }

  // ---- store: lane holds D[o = wave*16 + 4*lg + r][p = pt*16 + lm] ----
  float4 bv = *(const float4*)(bias + wave * 16 + 4 * lg);
  size_t ob = ((size_t)(b * 64 + wave * 16 + 4 * lg)) * 16384 + h * 128 + w0;
#pragma unroll
  for (int pt = 0; pt < 4; pt++) {
#pragma unroll
    for (int r = 0; r < 4; r++) {
      float bb = (r == 0) ? bv.x : (r == 1) ? bv.y : (r == 2) ? bv.z : bv.w;
      out[ob + (size_t)r * 16384 + pt * 16 + lm] = acc[pt][r] + bb;
    }
  }
}

extern "C" void kernel_launch(void* const* d_in, const int* in_sizes, int n_in,
                              void* d_out, int out_size, void* d_ws, size_t ws_size,
                              hipStream_t stream) {
  const float* x     = (const float*)d_in[0];
  const float* w_off = (const float*)d_in[1];
  const float* b_off = (const float*)d_in[2];
  const float* w     = (const float*)d_in[3];
  const float* b     = (const float*)d_in[4];
  float* out = (float*)d_out;
  char* ws = (char*)d_ws;

  u16*   whi     = (u16*)(ws);
  u16*   wlo     = (u16*)(ws + 73728);
  u16*   wofh    = (u16*)(ws + 147456);
  u16*   wofl    = (u16*)(ws + 184320);
  float* xtw     = (float*)(ws + 221184);
  float* off_pix = (float*)(ws + 16998400);

  prep_weights<<<64, 256, 0, stream>>>(w, w_off, whi, wlo, wofh, wofl);
  transpose_x<<<1024, 256, 0, stream>>>(x, xtw);
  offset_conv<<<512, 256, 0, stream>>>(xtw, wofh, wofl, b_off, off_pix);
  dcn_main<<<1024, 256, 0, stream>>>(xtw, off_pix, whi, wlo, b, out);
}